// Round 9
// baseline (5894.460 us; speedup 1.0000x reference)
//
#include <hip/hip_runtime.h>

// Dims
constexpr int TSTEPS = 512;
constexpr int FDIM   = 128;
constexpr int HDIM   = 256;
constexpr int G4H    = 1024;   // 4*H
constexpr int BATCH  = 256;
constexpr int NB     = 86;     // 84 blocks x 3 rows + 2 x 2 rows
constexpr int NKP    = 192;    // wpk k-pairs: kp<128 rker, kp in [128,192) kern
constexpr int TC     = 8;      // time-chunk
constexpr int NCH    = TSTEPS / TC;

typedef float        f32x2 __attribute__((ext_vector_type(2)));
typedef _Float16     h2    __attribute__((ext_vector_type(2)));
typedef unsigned int u32;
typedef u32          u32x4 __attribute__((ext_vector_type(4)));

#if defined(__has_builtin)
#if __has_builtin(__builtin_amdgcn_fdot2)
#define FDOT2(a, b, c) __builtin_amdgcn_fdot2((a), (b), (c), false)
#endif
#endif
#ifndef FDOT2
#define FDOT2(a, b, c) ((c) + (float)(a)[0] * (float)(b)[0] + (float)(a)[1] * (float)(b)[1])
#endif

__device__ __forceinline__ h2 as_h2(u32 v) { union { u32 u; h2 p; } c; c.u = v; return c.p; }
__device__ __forceinline__ u32 pack_h2(float a, float b) {
    union { h2 p; u32 u; } c; c.p = h2{(_Float16)a, (_Float16)b}; return c.u;
}
__device__ __forceinline__ float sigmf(float z) { return 1.f / (1.f + __expf(-z)); }
__device__ __forceinline__ float tanhf_fast(float z) {
    float a = fabsf(z);
    float e = __expf(-2.f * a);
    float r = (1.f - e) / (1.f + e);
    return z < 0.f ? -r : r;
}

// Repack weights to fp16 k-pairs: wpk[kp*1024 + c] = (w[2kp][c], w[2kp+1][c]).
// kp<128 from rker, kp>=128 from kern. 768 KB (ws_size >= 768 KB proven r5-8).
extern "C" __global__ void __launch_bounds__(256)
conv_wpk(const float* __restrict__ kern, const float* __restrict__ rker,
         u32* __restrict__ wpk)
{
    for (int i = blockIdx.x * 256 + threadIdx.x; i < NKP * G4H; i += gridDim.x * 256) {
        const int kp = i >> 10, c = i & 1023;
        float a, b;
        if (kp < 128) {
            a = rker[(size_t)(2 * kp) * G4H + c];
            b = rker[(size_t)(2 * kp + 1) * G4H + c];
        } else {
            const int k0 = (kp - 128) * 2;
            a = kern[(size_t)k0 * G4H + c];
            b = kern[(size_t)(k0 + 1) * G4H + c];
        }
        wpk[i] = pack_h2(a, b);
    }
}

// Zero-sync chunked LSTM, 4 waves/SIMD for latency hiding.
// r8 analysis: phase B was latency-bound at 2 waves/SIMD (9.6us/step vs 3.6us
// port floor); r6/r7 prove VGPR residency is compiler-blocked, so latency is
// hidden with MORE WAVES: 1024 threads (16 waves), thread owns ONE column of
// the 1024 gate-columns, full K=128 pairs -> per iter: 1 u32 weight load
// (ring-16), 1 uniform b128 h-read, 3 dot2. No K-split, no partial reduce.
// Small arrays only (~48 VGPR) -> no spill at the 1024-thread 64-reg cap.
extern "C" __global__ void __launch_bounds__(1024)
lstm_wide(const float* __restrict__ x, const u32* __restrict__ wpk,
          const float* __restrict__ w1, const float* __restrict__ b1,
          const float* __restrict__ w2, const float* __restrict__ b2,
          float* __restrict__ out)
{
    const int b    = blockIdx.x;
    const int base = (b < 84) ? 3 * b : 252 + 2 * (b - 84);
    const int nval = (b < 84) ? 3 : 2;
    const int tid  = threadIdx.x;

    // LDS: 48K + 12K + 2K + 1.2K = 63.3 KB
    __shared__ __align__(16) _Float16 xz16[TC * 3 * G4H];  // xz fp16 [(tc*3+r)*1024 + c]
    __shared__ __align__(16) float    ovl[3 * G4H];        // phase A: x16 staging / phase B: zfin [r][c]
    __shared__ __align__(16) u32      hpk[128 * 4];        // h fp16 pairs [kp][row(4)]
    __shared__ float hid[3][100];

    u32* x16u = (u32*)ovl;  // phase-A x staging: [rt(24)][fp(64)] fp16 pairs

    if (tid < 512) hpk[tid] = 0;  // h(0)=0 (ordered by A0 barrier)

    // P2 mapping: tid<768 -> row r2 = tid>>8, unit u2 = tid&255 (one cell/thread)
    const int r2 = tid >> 8, u2 = tid & 255;
    float cst = 0.f;

    const u32* wb = wpk + tid;              // phase-B: rker pair row kp at wb + kp*1024
    const u32* wa = wpk + 128 * G4H + tid;  // phase-A: kern pair row kp at wa + kp*1024

#pragma unroll 1
    for (int chnk = 0; chnk < NCH; ++chnk) {
        __syncthreads();  // A0: prev-chunk P2 (ovl/xz16 reads, hpk writes) done

        // ---- Stage x chunk -> x16u[rt][fp], rt = t*3+r (1536 pair-slots)
#pragma unroll
        for (int i = 0; i < 2; ++i) {
            const int idx = tid + i * 1024;
            if (idx < 1536) {
                const int rt = idx >> 6, fp = idx & 63;
                const int tt = rt / 3, rr = rt - 3 * tt;
                const int row = min(base + rr, BATCH - 1);
                const f32x2 xv = *reinterpret_cast<const f32x2*>(
                    x + ((size_t)row * TSTEPS + (chnk * TC + tt)) * FDIM + 2 * fp);
                x16u[idx] = pack_h2(xv[0], xv[1]);
            }
        }
        __syncthreads();  // A1: x16 ready

        // ---- Phase A: xz[rt][col tid] = sum_kp kern[kp][tid].x[rt][kp]
        {
            float acc[24];
#pragma unroll
            for (int rt = 0; rt < 24; ++rt) acc[rt] = 0.f;

            u32 Wc0[4], Wc1[4];
#pragma unroll
            for (int q = 0; q < 4; ++q) Wc0[q] = wa[(size_t)q * G4H];

            for (int g2 = 0; g2 < 16; g2 += 2) {
#pragma unroll
                for (int q = 0; q < 4; ++q)
                    Wc1[q] = wa[(size_t)(4 * (g2 + 1) + q) * G4H];
#pragma unroll
                for (int rt = 0; rt < 24; ++rt) {
                    const u32x4 X = *reinterpret_cast<const u32x4*>(&x16u[rt * 64 + 4 * g2]);
#pragma unroll
                    for (int q = 0; q < 4; ++q)
                        acc[rt] = FDOT2(as_h2(Wc0[q]), as_h2(X[q]), acc[rt]);
                }
                if (g2 + 2 < 16) {
#pragma unroll
                    for (int q = 0; q < 4; ++q)
                        Wc0[q] = wa[(size_t)(4 * (g2 + 2) + q) * G4H];
                }
#pragma unroll
                for (int rt = 0; rt < 24; ++rt) {
                    const u32x4 X = *reinterpret_cast<const u32x4*>(&x16u[rt * 64 + 4 * (g2 + 1)]);
#pragma unroll
                    for (int q = 0; q < 4; ++q)
                        acc[rt] = FDOT2(as_h2(Wc1[q]), as_h2(X[q]), acc[rt]);
                }
            }
#pragma unroll
            for (int rt = 0; rt < 24; ++rt)
                xz16[rt * G4H + tid] = (_Float16)acc[rt];
        }
        // phase A ends; T1 of step 0 orders x16u reads vs zfin overwrite

        // ---- Phase B: TC recurrence steps, rker-only stream
#pragma unroll 1
        for (int tc = 0; tc < TC; ++tc) {
            // Ring-16 prefetch issued before the barrier (completes during wait)
            u32 pf[16];
#pragma unroll
            for (int j = 0; j < 16; ++j) pf[j] = wb[(size_t)j * G4H];

            __syncthreads();  // T1: hpk(t) ready; zfin(prev)/x16u consumed

            float a0 = 0.f, a1 = 0.f, a2 = 0.f;
#pragma unroll
            for (int kp = 0; kp < 128; ++kp) {
                const u32 W = pf[kp & 15];
                if (kp < 112) pf[kp & 15] = wb[(size_t)(kp + 16) * G4H];
                const u32x4 H = *reinterpret_cast<const u32x4*>(&hpk[kp * 4]);  // broadcast
                const h2 wp2 = as_h2(W);
                a0 = FDOT2(wp2, as_h2(H[0]), a0);
                a1 = FDOT2(wp2, as_h2(H[1]), a1);
                a2 = FDOT2(wp2, as_h2(H[2]), a2);
            }
            ovl[0 * G4H + tid] = a0;   // zfin [r][c], stride-1 stores
            ovl[1 * G4H + tid] = a1;
            ovl[2 * G4H + tid] = a2;
            __syncthreads();  // T2: zfin ready

            // ---- P2: z + xz -> gates -> cell -> h(t+1) fp16 into hpk
            if (tid < 768) {
                float z[4];
#pragma unroll
                for (int gg = 0; gg < 4; ++gg)
                    z[gg] = ovl[r2 * G4H + gg * 256 + u2]
                          + (float)xz16[(tc * 3 + r2) * G4H + gg * 256 + u2];
                cst = sigmf(z[1]) * cst + sigmf(z[0]) * tanhf_fast(z[2]);
                const float hn = sigmf(z[3]) * tanhf_fast(cst);
                ((_Float16*)hpk)[(u2 >> 1) * 8 + r2 * 2 + (u2 & 1)] = (_Float16)hn;
            }
            // no barrier: T1(next) / A0(next chunk) orders hpk writes vs reads
        }
    }
    __syncthreads();

    // ---- Fused head: out[row] = relu(h@w1+b1)@w2 + b2 (h fp16 from hpk)
    if (tid < 300) {
        const int r = tid / 100, j = tid - r * 100;
        if (r < nval) {
            float a = b1[j];
            const _Float16* hph = (const _Float16*)hpk;
#pragma unroll 8
            for (int k = 0; k < HDIM; ++k)
                a += (float)hph[(k >> 1) * 8 + r * 2 + (k & 1)] * w1[k * 100 + j];
            hid[r][j] = fmaxf(a, 0.f);
        }
    }
    __syncthreads();
    if (tid < 3 && tid < nval) {
        float v = b2[0];
#pragma unroll 4
        for (int j = 0; j < 100; ++j) v += hid[tid][j] * w2[j];
        out[base + tid] = v;
    }
}

extern "C" void kernel_launch(void* const* d_in, const int* in_sizes, int n_in,
                              void* d_out, int out_size, void* d_ws, size_t ws_size,
                              hipStream_t stream)
{
    const float* x    = (const float*)d_in[0];
    const float* kern = (const float*)d_in[1];
    const float* rker = (const float*)d_in[2];
    const float* w1   = (const float*)d_in[3];
    const float* b1   = (const float*)d_in[4];
    const float* w2   = (const float*)d_in[5];
    const float* b2   = (const float*)d_in[6];
    float* out = (float*)d_out;

    u32* wpk = (u32*)d_ws;  // 768 KB

    conv_wpk<<<dim3(768), dim3(256), 0, stream>>>(kern, rker, wpk);
    lstm_wide<<<dim3(NB), dim3(1024), 0, stream>>>(x, wpk, w1, b1, w2, b2, out);
}